// Round 2
// baseline (1716.156 us; speedup 1.0000x reference)
//
#include <hip/hip_runtime.h>
#include <math.h>

// Problem constants (fixed by setup_inputs)
#define NB 8
#define NC 256
#define NH 128
#define NW 128
#define HW (NH*NW)        // 16384
#define NP 64
#define NK 2
#define CK 8              // feats channels per register buffer
#define CHALF 128         // channels per LDS staging phase

// Workspace float layout. Centers stored split into two C-halves:
// [h][p][c] with h in {0,1}, c in [0,128)
#define WS_CENTERS 0
#define WS_PSQ     (NP*NC)
#define WS_U       (WS_PSQ + NP)              // [p][k]
#define WS_AL      (WS_U + NP*NK)
#define WS_G2      (WS_AL + NP)

__global__ __launch_bounds__(64) void geo_precompute(
    const float* __restrict__ cm,        // (P,K)
    const float* __restrict__ alpha,     // (P,1)
    const float* __restrict__ gamma_,    // (P,1)
    const float* __restrict__ centers,   // (P,C)
    const float* __restrict__ geo,       // (P,1)
    float* __restrict__ ws)
{
    const int p = threadIdx.x;
    if (p >= NP) return;
    float s = 0.f;
    #pragma unroll
    for (int i = 0; i < NP; ++i) s += geo[i];
    const float scale = 1.0f + 0.1f * tanhf(s * (1.0f / NP));

    float psq = 0.f;
    for (int c = 0; c < NC; ++c) {
        float v = centers[p*NC + c] * scale;
        // split-half layout for the main kernel's 32 KB LDS phases
        ws[WS_CENTERS + (c / CHALF) * (NP*CHALF) + p*CHALF + (c % CHALF)] = v;
        psq += v * v;
    }
    ws[WS_PSQ + p] = psq;

    float b0 = cm[p*NK+0]; b0 *= b0;
    float b1 = cm[p*NK+1]; b1 *= b1;
    const float bs = b0 + b1;
    ws[WS_U + p*NK+0] = b0 / bs;
    ws[WS_U + p*NK+1] = b1 / bs;
    ws[WS_AL + p] = 0.99f / (1.0f + expf(-alpha[p]));
    ws[WS_G2 + p] = gamma_[p] * gamma_[p];
}

// One 4-prototype group: 8x ds_read_b128 (32 stage VGPRs max) + 32 FMAs,
// then a full scheduling barrier so the compiler cannot hoist the next
// group's LDS reads (unbounded hoisting caused the round-1 spill).
#define PROTO4(f, c0, PB)                                                     \
    {                                                                         \
        _Pragma("unroll")                                                     \
        for (int j = 0; j < 4; ++j) {                                         \
            const int p = (PB) + j;                                           \
            const float4 wa = *(const float4*)&sC[p*CHALF + (c0)];            \
            const float4 wb = *(const float4*)&sC[p*CHALF + (c0) + 4];        \
            float a = acc[p];                                                 \
            a += f[0]*wa.x; a += f[1]*wa.y; a += f[2]*wa.z; a += f[3]*wa.w;   \
            a += f[4]*wb.x; a += f[5]*wb.y; a += f[6]*wb.z; a += f[7]*wb.w;   \
            acc[p] = a;                                                       \
        }                                                                     \
        __builtin_amdgcn_sched_barrier(0);                                    \
    }

#define COMPUTE(f, c0)                                                        \
    {                                                                         \
        _Pragma("unroll")                                                     \
        for (int cc = 0; cc < CK; ++cc) xsq += f[cc]*f[cc];                   \
        _Pragma("unroll")                                                     \
        for (int pg = 0; pg < NP/4; ++pg) PROTO4(f, c0, pg*4)                 \
    }

__global__ __launch_bounds__(256, 3) void geo_main(
    const float* __restrict__ feats,     // (B,C,H,W)
    const float* __restrict__ ws,
    float* __restrict__ out)             // (B,3,H,W)
{
    __shared__ float sC[NP*CHALF];       // 32 KiB, [p][c-half]
    __shared__ float sPsq[NP];
    __shared__ float sU0[NP], sU1[NP];
    __shared__ float sAl[NP];
    __shared__ float sG2[NP];

    const int tid = threadIdx.x;
    if (tid < NP) {
        sPsq[tid] = ws[WS_PSQ + tid];
        sAl[tid]  = ws[WS_AL + tid];
        sG2[tid]  = ws[WS_G2 + tid];
        sU0[tid]  = ws[WS_U + 2*tid + 0];
        sU1[tid]  = ws[WS_U + 2*tid + 1];
    }

    const int pix = blockIdx.x * 256 + tid;     // exact grid: B*HW threads
    const int b  = pix >> 14;
    const int hw = pix & (HW - 1);
    const float* __restrict__ fp = feats + (size_t)b * NC * HW + hw;

    float acc[NP];
    #pragma unroll
    for (int p = 0; p < NP; ++p) acc[p] = 0.f;
    float xsq = 0.f;

    float fA[CK], fB[CK];

    for (int h = 0; h < 2; ++h) {
        __syncthreads();   // previous phase's readers done before overwrite
        #pragma unroll
        for (int i = tid*4; i < NP*CHALF; i += 256*4) {
            *(float4*)&sC[i] = *(const float4*)&ws[WS_CENTERS + h*(NP*CHALF) + i];
        }
        __syncthreads();

        const float* __restrict__ fph = fp + (size_t)h * CHALF * HW;

        // prologue: load chunk 0 of this phase
        #pragma unroll
        for (int cc = 0; cc < CK; ++cc) fA[cc] = fph[cc * HW];

        #pragma unroll 1
        for (int ci = 0; ci < CHALF/(2*CK); ++ci) {   // 8 iterations
            const int c0 = ci * (2*CK);

            // prefetch chunk c0+CK into fB (sits before COMPUTE's barriers)
            #pragma unroll
            for (int cc = 0; cc < CK; ++cc) fB[cc] = fph[(c0 + CK + cc) * HW];

            COMPUTE(fA, c0)

            // prefetch chunk c0+2*CK into fA (window between the two COMPUTEs)
            if (ci + 1 < CHALF/(2*CK)) {
                #pragma unroll
                for (int cc = 0; cc < CK; ++cc) fA[cc] = fph[(c0 + 2*CK + cc) * HW];
            }

            COMPUTE(fB, c0 + CK)
        }
    }

    // Per-pixel sequential scan over prototypes (registers only)
    float ms0 = 0.f, ms1 = 0.f, mt = 1.f;
    #pragma unroll
    for (int p = 0; p < NP; ++p) {
        const float d = 0.5f * (xsq - 2.f * acc[p] + sPsq[p]);
        const float sact = sAl[p] * __expf(-sG2[p] * d);
        const float mth = 1.f - sact;
        const float m0 = sact * sU0[p];
        const float m1 = sact * sU1[p];
        ms0 = ms0 * (m0 + mth) + m0 * mt;
        ms1 = ms1 * (m1 + mth) + m1 * mt;
        mt *= mth;
    }

    const float inv = 1.f / (ms0 + ms1 + mt + 1e-12f);
    float* __restrict__ op = out + (size_t)b * 3 * HW + hw;
    op[0*HW] = ms0 * inv;
    op[1*HW] = ms1 * inv;
    op[2*HW] = mt  * inv;
}

extern "C" void kernel_launch(void* const* d_in, const int* in_sizes, int n_in,
                              void* d_out, int out_size, void* d_ws, size_t ws_size,
                              hipStream_t stream) {
    const float* feats   = (const float*)d_in[0];
    // d_in[1] = geo_context (unused by reference)
    const float* cm      = (const float*)d_in[2];
    const float* alpha   = (const float*)d_in[3];
    const float* gamma_  = (const float*)d_in[4];
    const float* centers = (const float*)d_in[5];
    const float* geo     = (const float*)d_in[6];
    float* out = (float*)d_out;
    float* ws  = (float*)d_ws;

    geo_precompute<<<1, 64, 0, stream>>>(cm, alpha, gamma_, centers, geo, ws);

    const int total = NB * HW;                 // 131072 pixels
    geo_main<<<total / 256, 256, 0, stream>>>(feats, ws, out);
}

// Round 3
// 102.230 us; speedup vs baseline: 16.7872x; 16.7872x over previous
//
#include <hip/hip_runtime.h>
#include <math.h>

// Problem constants (fixed by setup_inputs)
#define NB 8
#define NC 256
#define NH 128
#define NW 128
#define HW (NH*NW)        // 16384
#define NP 64
#define NK 2
#define PXB 64            // pixels per block (one wave-width)
#define PW 16             // prototypes per wave (4 waves cover NP=64)
#define CCH 4             // channels per inner chunk

// Workspace float layout (centers plain [p][c])
#define WS_CENTERS 0
#define WS_PSQ     (NP*NC)
#define WS_U       (WS_PSQ + NP)              // [p][k]
#define WS_AL      (WS_U + NP*NK)
#define WS_G2      (WS_AL + NP)

__global__ __launch_bounds__(64) void geo_precompute(
    const float* __restrict__ cm,        // (P,K)
    const float* __restrict__ alpha,     // (P,1)
    const float* __restrict__ gamma_,    // (P,1)
    const float* __restrict__ centers,   // (P,C)
    const float* __restrict__ geo,       // (P,1)
    float* __restrict__ ws)
{
    const int p = threadIdx.x;
    if (p >= NP) return;
    float s = 0.f;
    #pragma unroll
    for (int i = 0; i < NP; ++i) s += geo[i];
    const float scale = 1.0f + 0.1f * tanhf(s * (1.0f / NP));

    float psq = 0.f;
    for (int c = 0; c < NC; ++c) {
        float v = centers[p*NC + c] * scale;
        ws[WS_CENTERS + p*NC + c] = v;
        psq += v * v;
    }
    ws[WS_PSQ + p] = psq;

    float b0 = cm[p*NK+0]; b0 *= b0;
    float b1 = cm[p*NK+1]; b1 *= b1;
    const float bs = b0 + b1;
    ws[WS_U + p*NK+0] = b0 / bs;
    ws[WS_U + p*NK+1] = b1 / bs;
    ws[WS_AL + p] = 0.99f / (1.0f + expf(-alpha[p]));
    ws[WS_G2 + p] = gamma_[p] * gamma_[p];
}

// Block = 256 threads (4 waves), owns 64 pixels.
// Wave w computes prototypes [16w, 16w+16) for all 64 pixels -> acc[16]/thread.
// Exchange s_act through LDS [p][px] (conflict-free), then wave 0 scans.
__global__ __launch_bounds__(256) void geo_main(
    const float* __restrict__ feats,     // (B,C,H,W)
    const float* __restrict__ ws,
    float* __restrict__ out)             // (B,3,H,W)
{
    __shared__ float sS[NP][PXB];        // 16 KiB: s_act [p][px]

    const int tid  = threadIdx.x;
    const int lane = tid & 63;
    // wave index, made formally wave-uniform so center addresses are scalar
    const int wu = __builtin_amdgcn_readfirstlane(tid >> 6);

    const int pix = blockIdx.x * PXB + lane;   // exact grid
    const int b   = pix >> 14;
    const int hw  = pix & (HW - 1);
    const float* __restrict__ fp  = feats + (size_t)b * NC * HW + hw;
    const float* __restrict__ cen = ws + WS_CENTERS + wu * PW * NC;

    float acc[PW];
    #pragma unroll
    for (int j = 0; j < PW; ++j) acc[j] = 0.f;
    float xsq = 0.f;

    #pragma unroll 1
    for (int ci = 0; ci < NC/CCH; ++ci) {      // 64 chunks of 4 channels
        const int c0 = ci * CCH;
        const float f0 = fp[(c0+0) * HW];
        const float f1 = fp[(c0+1) * HW];
        const float f2 = fp[(c0+2) * HW];
        const float f3 = fp[(c0+3) * HW];
        xsq += f0*f0; xsq += f1*f1; xsq += f2*f2; xsq += f3*f3;
        #pragma unroll
        for (int j = 0; j < PW; ++j) {
            const float4 w4 = *(const float4*)&cen[j*NC + c0];
            float a = acc[j];
            a += f0*w4.x; a += f1*w4.y; a += f2*w4.z; a += f3*w4.w;
            acc[j] = a;
        }
    }

    // finish s_act for this wave's 16 prototypes (exp spread over all 4 waves)
    {
        const float* __restrict__ psq = ws + WS_PSQ;
        const float* __restrict__ al  = ws + WS_AL;
        const float* __restrict__ g2  = ws + WS_G2;
        #pragma unroll
        for (int j = 0; j < PW; ++j) {
            const int p = wu * PW + j;
            const float d = 0.5f * (xsq - 2.f * acc[j] + psq[p]);
            sS[p][lane] = al[p] * __expf(-g2[p] * d);
        }
    }
    __syncthreads();

    // wave 0: sequential evidential scan per pixel (64 steps, registers only)
    if (tid < PXB) {
        const float* __restrict__ U = ws + WS_U;
        float ms0 = 0.f, ms1 = 0.f, mt = 1.f;
        #pragma unroll
        for (int p = 0; p < NP; ++p) {
            const float s   = sS[p][tid];
            const float mth = 1.f - s;
            const float m0  = s * U[2*p+0];
            const float m1  = s * U[2*p+1];
            ms0 = ms0 * (m0 + mth) + m0 * mt;
            ms1 = ms1 * (m1 + mth) + m1 * mt;
            mt *= mth;
        }
        const float inv = 1.f / (ms0 + ms1 + mt + 1e-12f);
        float* __restrict__ op = out + (size_t)b * 3 * HW + hw;
        op[0*HW] = ms0 * inv;
        op[1*HW] = ms1 * inv;
        op[2*HW] = mt  * inv;
    }
}

extern "C" void kernel_launch(void* const* d_in, const int* in_sizes, int n_in,
                              void* d_out, int out_size, void* d_ws, size_t ws_size,
                              hipStream_t stream) {
    const float* feats   = (const float*)d_in[0];
    // d_in[1] = geo_context (unused by reference)
    const float* cm      = (const float*)d_in[2];
    const float* alpha   = (const float*)d_in[3];
    const float* gamma_  = (const float*)d_in[4];
    const float* centers = (const float*)d_in[5];
    const float* geo     = (const float*)d_in[6];
    float* out = (float*)d_out;
    float* ws  = (float*)d_ws;

    geo_precompute<<<1, 64, 0, stream>>>(cm, alpha, gamma_, centers, geo, ws);

    const int total = NB * HW;                 // 131072 pixels
    geo_main<<<total / PXB, 256, 0, stream>>>(feats, ws, out);
}